// Round 2
// baseline (117.123 us; speedup 1.0000x reference)
//
#include <hip/hip_runtime.h>
#include <math.h>

#define M_   2049
#define B_   16
#define N_   1024
#define TAU_ 2.821e-5
#define PI_  3.14159265358979323846
#define TWO_PI_ 6.283185307179586476925286766559

#define CV_SPLIT 16     // mp-split for conv
#define MPAD     2052   // padded m-stride for conv partials (multiple of 4)

#define K1_SCAT  16     // one scatter block per batch (plain-store gsum)
#define K1_HT    17     // d-tiles of 64 for h (plain-store hhalf)

// LDS swizzle for the conv h-window: pad 1 double per 4 so the FIR
// lane-stride-4 read (word stride 8 -> 16-way conflict raw) becomes word
// stride 10 -> 4-way aliasing (~free). [R7: conflicts 6.4M->76K]
#define SW(i) ((i) + ((i) >> 2))

// ===========================================================================
// Kernel 1: blocks [0,16): full gsum[b] in LDS (atomics local), plain store.
//           blocks [16,33): h for a 64-wide d-tile, 4-way j-split in-block,
//           LDS reduce, plain store.  No global atomics -> NO memset needed.
// ===========================================================================
__global__ __launch_bounds__(256)
void spread_h2(const float* __restrict__ x,
               const float* __restrict__ s0, const float* __restrict__ a0,
               const float* __restrict__ s1, const float* __restrict__ a1,
               double* __restrict__ gsum, double* __restrict__ hhalf) {
    __shared__ double smem[4609];
    const int bx  = blockIdx.x;
    const int tid = threadIdx.x;

    if (bx < K1_SCAT) {
        // ---- full-batch scatter: block owns gsum[b][:] ----
        const int b = bx;
        for (int i = tid; i < M_; i += 256) smem[i] = 0.0;
        __syncthreads();
        const double du      = TWO_PI_ / (double)M_;
        const double inv4tau = 1.0 / (4.0 * TAU_);
        for (int c = 0; c < 4; ++c) {
            const int p = (c << 8) + tid;                  // 4 points per thread
            const double xv = (double)x[(b << 10) + p];
            const double u  = xv * (TWO_PI_ / 10.0);
            const int mc = (int)(xv * ((double)M_ / 10.0) + 0.5);  // == u/du
            const int start = mc - 33;                     // window mc-33..mc+34
            for (int i = 0; i < 68; ++i) {
                int m = start + i;
                if (m >= 0 && m < M_) {
                    double d = u - du * (double)m;
                    double t = d * d * inv4tau;
                    if (t < 88.0) atomicAdd(&smem[m], (double)__expf(-(float)t));
                }
            }
        }
        __syncthreads();
        for (int i = tid; i < M_; i += 256) gsum[b * M_ + i] = smem[i];
    } else {
        // ---- h for d-tile: hhalf[d] = j0 + sum_j cf(j) cos(2pi j d / M) ----
        const int dtile = bx - K1_SCAT;
        double* costab = smem;            // 2049
        double* cf0    = smem + 2049;     // 1024
        double* cf1    = smem + 3073;     // 1024
        double* red    = smem + 4097;     // 512
        const double ang0 = TWO_PI_ / (double)M_;
        for (int i = tid; i <= 1024; i += 256) {
            double v = cos(ang0 * (double)i);
            costab[i] = v;
            if (i > 0) costab[M_ - i] = v;   // cos(2pi(M-i)/M) = cos(2pi i/M)
        }
        const double sA = 5.0 * (double)s0[0], sB = 5.0 * (double)s1[0];
        const double amp0 = (double)a0[0],     amp1 = (double)a1[0];
        for (int jj = tid; jj < 1024; jj += 256) {
            double j  = (double)(jj + 1);
            double k2 = j * j;
            double dec2 = (PI_ / TAU_) * exp(2.0 * TAU_ * k2);   // deconv^2
            double base = 2.0 * (10.0 / TWO_PI_) * dec2 / (double)M_;
            cf0[jj] = base * (-amp0 * 4.0 * PI_ / (k2 + sA * sA));
            double den = k2 + sB * sB;
            cf1[jj] = base * (amp1 * 4.0 * PI_ / (den * den));
        }
        __syncthreads();
        const int dl = tid & 63;          // lane within d-tile
        const int jq = tid >> 6;          // j-quarter 0..3
        const int d  = (dtile << 6) + dl;
        double acc0 = 0.0, acc1 = 0.0;
        if (d <= 1024) {
            const int jlo = (jq << 8) + 1;
            int r = (int)(((long long)jlo * (long long)d) % M_);
            #pragma unroll 4
            for (int jj = 0; jj < 256; ++jj) {
                double cv_ = costab[r];
                acc0 += cf0[(jq << 8) + jj] * cv_;   // wave-uniform -> broadcast
                acc1 += cf1[(jq << 8) + jj] * cv_;
                r += d; if (r >= M_) r -= M_;
            }
        }
        red[(jq << 6) + dl]       = acc0;
        red[256 + (jq << 6) + dl] = acc1;
        __syncthreads();
        if (tid < 64) {
            const int dd = (dtile << 6) + tid;
            if (dd <= 1024) {
                const double w0base = (10.0 / TWO_PI_) * (PI_ / TAU_) / (double)M_;
                double h0 = w0base * (-amp0 * 4.0 * PI_ / (sA * sA))
                          + red[tid] + red[64 + tid] + red[128 + tid] + red[192 + tid];
                double h1 = w0base * (amp1 * 4.0 * PI_ / ((sB * sB) * (sB * sB)))
                          + red[256 + tid] + red[320 + tid] + red[384 + tid] + red[448 + tid];
                hhalf[dd]        = h0;
                hhalf[1025 + dd] = h1;
            }
        }
    }
}

// ===========================================================================
// Kernel 2: part[s][b][c][m] = sum over mp-chunk s of gsum[b][mp]*h_c[(m-mp)%M]
// FIR with swizzled LDS window; gsum chunk staged in LDS (broadcast reads);
// register-role-rotated 4-tap unroll (zero f64 movs per tap).
// ===========================================================================
__global__ void conv_kernel(const double* __restrict__ gsum, const double* __restrict__ hhalf,
                            double* __restrict__ part) {
    __shared__ double w0s[1456];        // SW(1153) max
    __shared__ double w1s[1456];
    __shared__ double red[512];
    __shared__ double gls[132];
    const int mt = blockIdx.x;          // 0 or 1
    const int s  = blockIdx.y;          // mp-chunk
    const int b  = blockIdx.z;
    const int m0  = mt * 1024;
    const int p0  = (s * M_) / CV_SPLIT;
    const int p1  = ((s + 1) * M_) / CV_SPLIT;
    const int len = p1 - p0;            // 128 or 129
    const int wcount = 1024 + len;
    int base = m0 - (p0 + len - 1);
    while (base < 0) base += M_;
    for (int i = threadIdx.x; i < wcount; i += 256) {
        int idx = base + i;
        while (idx >= M_) idx -= M_;
        int dd = (idx > 1024) ? (M_ - idx) : idx;   // h even: h[d]=hhalf[min(d,M-d)]
        w0s[SW(i)] = hhalf[dd];
        w1s[SW(i)] = hhalf[1025 + dd];
    }
    for (int i = threadIdx.x; i < len; i += 256)
        gls[i] = gsum[(size_t)b * M_ + p0 + i];
    __syncthreads();

    const int q = 4 * threadIdx.x + len - 1;
    double A0 = w0s[SW(q)], A1 = w0s[SW(q+1)], A2 = w0s[SW(q+2)], A3 = w0s[SW(q+3)];
    double C0 = w1s[SW(q)], C1 = w1s[SW(q+1)], C2 = w1s[SW(q+2)], C3 = w1s[SW(q+3)];
    double a00=0.0,a01=0.0,a02=0.0,a03=0.0, a10=0.0,a11=0.0,a12=0.0,a13=0.0;
    int j = q, tt = 0;
    // Rotation: tap t, role r uses W(q - t + r); after 4 taps roles realign.
    for (; tt + 4 <= len; tt += 4) {
        double g;
        g = gls[tt];
        a00 += g*A0; a01 += g*A1; a02 += g*A2; a03 += g*A3;
        a10 += g*C0; a11 += g*C1; a12 += g*C2; a13 += g*C3;
        A3 = w0s[SW(j-1)]; C3 = w1s[SW(j-1)];
        g = gls[tt+1];
        a00 += g*A3; a01 += g*A0; a02 += g*A1; a03 += g*A2;
        a10 += g*C3; a11 += g*C0; a12 += g*C1; a13 += g*C2;
        A2 = w0s[SW(j-2)]; C2 = w1s[SW(j-2)];
        g = gls[tt+2];
        a00 += g*A2; a01 += g*A3; a02 += g*A0; a03 += g*A1;
        a10 += g*C2; a11 += g*C3; a12 += g*C0; a13 += g*C1;
        A1 = w0s[SW(j-3)]; C1 = w1s[SW(j-3)];
        g = gls[tt+3];
        a00 += g*A1; a01 += g*A2; a02 += g*A3; a03 += g*A0;
        a10 += g*C1; a11 += g*C2; a12 += g*C3; a13 += g*C0;
        A0 = w0s[SW(j-4)]; C0 = w1s[SW(j-4)];
        j -= 4;
    }
    for (; tt < len; ++tt) {            // tail: at most 1 (len = 128/129)
        double g = gls[tt];
        a00 += g*A0; a01 += g*A1; a02 += g*A2; a03 += g*A3;
        a10 += g*C0; a11 += g*C1; a12 += g*C2; a13 += g*C3;
    }
    {
        double* pv = part + (((size_t)s * B_ + b) * 2) * MPAD + m0 + 4 * threadIdx.x;
        pv[0]        = a00; pv[1]        = a01; pv[2]        = a02; pv[3]        = a03;
        pv[MPAD + 0] = a10; pv[MPAD + 1] = a11; pv[MPAD + 2] = a12; pv[MPAD + 3] = a13;
    }
    // m = 2048 side-reduction — mt==1 blocks only (mt uniform per block)
    if (mt == 1) {
        double t0 = 0.0, t1 = 0.0;
        if (threadIdx.x < len) {
            double g = gls[threadIdx.x];
            int qq = 1023 + len - threadIdx.x;
            t0 = g * w0s[SW(qq)];
            t1 = g * w1s[SW(qq)];
        }
        red[threadIdx.x]       = t0;
        red[256 + threadIdx.x] = t1;
        __syncthreads();
        for (int off = 128; off > 0; off >>= 1) {
            if (threadIdx.x < off) {
                red[threadIdx.x]       += red[threadIdx.x + off];
                red[256 + threadIdx.x] += red[256 + threadIdx.x + off];
            }
            __syncthreads();
        }
        if (threadIdx.x == 0) {
            double* pv = part + (((size_t)s * B_ + b) * 2) * MPAD;
            pv[2048]        = red[0];
            pv[MPAD + 2048] = red[256];
        }
    }
}

// ===========================================================================
// Kernel 3: one block per batch.  Stage conv[b] = sum_s part[s][b] into LDS,
// then fmm gather for all 1024 points of the batch from LDS.
// ===========================================================================
__global__ __launch_bounds__(256)
void reduce_fmm(const float* __restrict__ x, const double* __restrict__ part,
                float* __restrict__ out) {
    __shared__ double convs[2 * M_];    // 32.8 KB
    const int b   = blockIdx.x;
    const int tid = threadIdx.x;
    const size_t sstride = (size_t)B_ * 2 * MPAD;
    for (int ch = 0; ch < 2; ++ch) {
        const size_t off0 = ((size_t)b * 2 + ch) * MPAD;
        for (int m = tid; m < M_; m += 256) {
            double acc = 0.0;
            #pragma unroll
            for (int k = 0; k < CV_SPLIT; ++k)
                acc += part[(size_t)k * sstride + off0 + m];
            convs[ch * M_ + m] = acc;
        }
    }
    __syncthreads();
    const double du      = TWO_PI_ / (double)M_;
    const double inv4tau = 1.0 / (4.0 * TAU_);
    for (int c = 0; c < 4; ++c) {
        const int p  = (b << 10) + (c << 8) + tid;     // global point id
        const double xv = (double)x[p];
        const double u  = xv * (TWO_PI_ / 10.0);
        int mc = (int)(xv * ((double)M_ / 10.0) + 0.5);
        int lo = mc - 34; if (lo < 0) lo = 0;
        int hi = mc + 34; if (hi > M_ - 1) hi = M_ - 1;
        double av0 = 0.0, av1 = 0.0;
        for (int m = lo; m <= hi; ++m) {
            double d = u - du * (double)m;
            double g = (double)__expf(-(float)(d * d * inv4tau));
            av0 += g * convs[m];
            av1 += g * convs[M_ + m];
        }
        out[p * 2 + 0] = (float)(av0 / (double)M_);
        out[p * 2 + 1] = (float)(av1 / (double)M_);
    }
}

// ---------------------------------------------------------------------------
extern "C" void kernel_launch(void* const* d_in, const int* in_sizes, int n_in,
                              void* d_out, int out_size, void* d_ws, size_t ws_size,
                              hipStream_t stream) {
    (void)in_sizes; (void)n_in; (void)out_size; (void)ws_size;
    const float* x  = (const float*)d_in[0];
    const float* s0 = (const float*)d_in[1];
    const float* a0 = (const float*)d_in[2];
    const float* s1 = (const float*)d_in[3];
    const float* a1 = (const float*)d_in[4];
    float* out = (float*)d_out;

    // Workspace layout (f64): [gsum B*M | hhalf 2*1025 | part]  — no zeroing
    // needed anywhere: every element is plain-stored by its owning block.
    double* gsum  = (double*)d_ws;             // 32784
    double* hhalf = gsum + B_ * M_;            // 2050
    double* part  = hhalf + 2 * 1025;          // CV_SPLIT*B_*2*MPAD (~8.4 MB)

    hipLaunchKernelGGL(spread_h2, dim3(K1_SCAT + K1_HT), dim3(256), 0, stream,
                       x, s0, a0, s1, a1, gsum, hhalf);
    hipLaunchKernelGGL(conv_kernel, dim3(2, CV_SPLIT, B_), dim3(256), 0, stream,
                       gsum, hhalf, part);
    hipLaunchKernelGGL(reduce_fmm, dim3(B_), dim3(256), 0, stream,
                       x, part, out);
}

// Round 3
// 97.792 us; speedup vs baseline: 1.1977x; 1.1977x over previous
//
#include <hip/hip_runtime.h>
#include <math.h>

#define M_   2049
#define B_   16
#define N_   1024
#define TAU_ 2.821e-5
#define PI_  3.14159265358979323846
#define TWO_PI_ 6.283185307179586476925286766559

#define CV_SPLIT 16     // mp-split for conv
#define MPAD     2052   // padded m-stride for conv partials (multiple of 4)

#define GS_CH    8      // scatter chunks per batch (128 blocks total)
#define HT_BLKS  33     // h d-tiles of 32 (33*32 = 1056 >= 1025)
#define FMM_QB   4      // fmm blocks per batch (64 blocks total)

// LDS swizzle for the conv h-window: pad 1 double per 4 so the FIR
// lane-stride-4 read (word stride 8 -> 16-way conflict raw) becomes word
// stride 10 -> 4-way aliasing (~free). [R7: conflicts 6.4M->76K]
#define SW(i) ((i) + ((i) >> 2))

// ===========================================================================
// Kernel 1:
//  blocks [0,128): scatter chunk ch of batch b -> gsum_part[ch][b][:] (plain
//                  store; 128 pts/block, 2 lanes/pt, 34 taps -> 8.7K LDS
//                  atomics/block, the proven-fast contention scale).
//  blocks [128,161): h for a 32-wide d-tile, 8-way j-split in-block, LDS
//                  reduce, plain store.  No global atomics -> NO memset.
// ===========================================================================
__global__ __launch_bounds__(256)
void spread_h3(const float* __restrict__ x,
               const float* __restrict__ s0, const float* __restrict__ a0,
               const float* __restrict__ s1, const float* __restrict__ a1,
               double* __restrict__ gsum_part, double* __restrict__ hhalf) {
    __shared__ double smem[4609];
    const int bx  = blockIdx.x;
    const int tid = threadIdx.x;

    if (bx < GS_CH * B_) {
        // ---- scatter partial: block owns gsum_part[ch][b][:] ----
        const int b  = bx >> 3;
        const int ch = bx & (GS_CH - 1);
        for (int i = tid; i < M_; i += 256) smem[i] = 0.0;
        __syncthreads();
        const int pl  = tid >> 1;          // local point 0..127
        const int sub = tid & 1;           // half-window 0/1
        const double du      = TWO_PI_ / (double)M_;
        const double inv4tau = 1.0 / (4.0 * TAU_);
        const double xv = (double)x[(b << 10) + (ch << 7) + pl];
        const double u  = xv * (TWO_PI_ / 10.0);
        const int mc = (int)(xv * ((double)M_ / 10.0) + 0.5);   // == u/du
        const int start = mc - 33 + sub * 34;                   // mc-33..mc+34
        for (int i = 0; i < 34; ++i) {
            int m = start + i;
            if (m >= 0 && m < M_) {
                double d = u - du * (double)m;
                double t = d * d * inv4tau;
                if (t < 88.0) atomicAdd(&smem[m], (double)__expf(-(float)t));
            }
        }
        __syncthreads();
        double* gp = gsum_part + ((size_t)ch * B_ + b) * M_;
        for (int i = tid; i < M_; i += 256) gp[i] = smem[i];
    } else {
        // ---- h tile: hhalf[d] = j0 + sum_j cf(j) cos(2pi j d / M) ----
        const int dtile = bx - GS_CH * B_;
        double* costab = smem;            // 2049
        double* cf0    = smem + 2049;     // 1024
        double* cf1    = smem + 3073;     // 1024
        double* red    = smem + 4097;     // 512
        const double ang0 = TWO_PI_ / (double)M_;
        for (int i = tid; i <= 1024; i += 256) {
            double v = cos(ang0 * (double)i);
            costab[i] = v;
            if (i > 0) costab[M_ - i] = v;   // cos(2pi(M-i)/M) = cos(2pi i/M)
        }
        const double sA = 5.0 * (double)s0[0], sB = 5.0 * (double)s1[0];
        const double amp0 = (double)a0[0],     amp1 = (double)a1[0];
        for (int jj = tid; jj < 1024; jj += 256) {
            double j  = (double)(jj + 1);
            double k2 = j * j;
            double dec2 = (PI_ / TAU_) * exp(2.0 * TAU_ * k2);   // deconv^2
            double base = 2.0 * (10.0 / TWO_PI_) * dec2 / (double)M_;
            cf0[jj] = base * (-amp0 * 4.0 * PI_ / (k2 + sA * sA));
            double den = k2 + sB * sB;
            cf1[jj] = base * (amp1 * 4.0 * PI_ / (den * den));
        }
        __syncthreads();
        const int dl = tid & 31;          // lane within d-tile
        const int jq = tid >> 5;          // j-eighth 0..7
        const int d  = (dtile << 5) + dl;
        double acc0 = 0.0, acc1 = 0.0;
        if (d <= 1024) {
            const int jlo = (jq << 7) + 1;
            int r = (int)(((long long)jlo * (long long)d) % M_);
            #pragma unroll 4
            for (int jj = 0; jj < 128; ++jj) {
                double cv_ = costab[r];
                acc0 += cf0[(jq << 7) + jj] * cv_;
                acc1 += cf1[(jq << 7) + jj] * cv_;
                r += d; if (r >= M_) r -= M_;
            }
        }
        red[tid]       = acc0;
        red[256 + tid] = acc1;
        __syncthreads();
        if (tid < 32) {
            const int dd = (dtile << 5) + tid;
            if (dd <= 1024) {
                const double w0base = (10.0 / TWO_PI_) * (PI_ / TAU_) / (double)M_;
                double h0 = w0base * (-amp0 * 4.0 * PI_ / (sA * sA));
                double h1 = w0base * (amp1 * 4.0 * PI_ / ((sB * sB) * (sB * sB)));
                #pragma unroll
                for (int q = 0; q < 8; ++q) {
                    h0 += red[(q << 5) + tid];
                    h1 += red[256 + (q << 5) + tid];
                }
                hhalf[dd]        = h0;
                hhalf[1025 + dd] = h1;
            }
        }
    }
}

// ===========================================================================
// Kernel 2: part[s][b][c][m] = sum over mp-chunk s of gsum[b][mp]*h_c[(m-mp)%M]
// FIR with swizzled LDS window; gsum chunk staged in LDS (summing the 8
// scatter partials); register-role-rotated 4-tap unroll (zero movs/tap).
// ===========================================================================
__global__ void conv_kernel(const double* __restrict__ gsum_part,
                            const double* __restrict__ hhalf,
                            double* __restrict__ part) {
    __shared__ double w0s[1456];        // SW(1153) max
    __shared__ double w1s[1456];
    __shared__ double red[512];
    __shared__ double gls[132];
    const int mt = blockIdx.x;          // 0 or 1
    const int s  = blockIdx.y;          // mp-chunk
    const int b  = blockIdx.z;
    const int m0  = mt * 1024;
    const int p0  = (s * M_) / CV_SPLIT;
    const int p1  = ((s + 1) * M_) / CV_SPLIT;
    const int len = p1 - p0;            // 128 or 129
    const int wcount = 1024 + len;
    int base = m0 - (p0 + len - 1);
    while (base < 0) base += M_;
    for (int i = threadIdx.x; i < wcount; i += 256) {
        int idx = base + i;
        while (idx >= M_) idx -= M_;
        int dd = (idx > 1024) ? (M_ - idx) : idx;   // h even: h[d]=hhalf[min(d,M-d)]
        w0s[SW(i)] = hhalf[dd];
        w1s[SW(i)] = hhalf[1025 + dd];
    }
    for (int i = threadIdx.x; i < len; i += 256) {
        double acc = 0.0;
        #pragma unroll
        for (int ch = 0; ch < GS_CH; ++ch)
            acc += gsum_part[((size_t)ch * B_ + b) * M_ + p0 + i];
        gls[i] = acc;
    }
    __syncthreads();

    const int q = 4 * threadIdx.x + len - 1;
    double A0 = w0s[SW(q)], A1 = w0s[SW(q+1)], A2 = w0s[SW(q+2)], A3 = w0s[SW(q+3)];
    double C0 = w1s[SW(q)], C1 = w1s[SW(q+1)], C2 = w1s[SW(q+2)], C3 = w1s[SW(q+3)];
    double a00=0.0,a01=0.0,a02=0.0,a03=0.0, a10=0.0,a11=0.0,a12=0.0,a13=0.0;
    int j = q, tt = 0;
    // Rotation: tap t, role r uses W(q - t + r); after 4 taps roles realign.
    for (; tt + 4 <= len; tt += 4) {
        double g;
        g = gls[tt];
        a00 += g*A0; a01 += g*A1; a02 += g*A2; a03 += g*A3;
        a10 += g*C0; a11 += g*C1; a12 += g*C2; a13 += g*C3;
        A3 = w0s[SW(j-1)]; C3 = w1s[SW(j-1)];
        g = gls[tt+1];
        a00 += g*A3; a01 += g*A0; a02 += g*A1; a03 += g*A2;
        a10 += g*C3; a11 += g*C0; a12 += g*C1; a13 += g*C2;
        A2 = w0s[SW(j-2)]; C2 = w1s[SW(j-2)];
        g = gls[tt+2];
        a00 += g*A2; a01 += g*A3; a02 += g*A0; a03 += g*A1;
        a10 += g*C2; a11 += g*C3; a12 += g*C0; a13 += g*C1;
        A1 = w0s[SW(j-3)]; C1 = w1s[SW(j-3)];
        g = gls[tt+3];
        a00 += g*A1; a01 += g*A2; a02 += g*A3; a03 += g*A0;
        a10 += g*C1; a11 += g*C2; a12 += g*C3; a13 += g*C0;
        A0 = w0s[SW(j-4)]; C0 = w1s[SW(j-4)];
        j -= 4;
    }
    for (; tt < len; ++tt) {            // tail: at most 1 (len = 128/129)
        double g = gls[tt];
        a00 += g*A0; a01 += g*A1; a02 += g*A2; a03 += g*A3;
        a10 += g*C0; a11 += g*C1; a12 += g*C2; a13 += g*C3;
    }
    {
        double* pv = part + (((size_t)s * B_ + b) * 2) * MPAD + m0 + 4 * threadIdx.x;
        pv[0]        = a00; pv[1]        = a01; pv[2]        = a02; pv[3]        = a03;
        pv[MPAD + 0] = a10; pv[MPAD + 1] = a11; pv[MPAD + 2] = a12; pv[MPAD + 3] = a13;
    }
    // m = 2048 side-reduction — mt==1 blocks only (mt uniform per block)
    if (mt == 1) {
        double t0 = 0.0, t1 = 0.0;
        if (threadIdx.x < len) {
            double g = gls[threadIdx.x];
            int qq = 1023 + len - threadIdx.x;
            t0 = g * w0s[SW(qq)];
            t1 = g * w1s[SW(qq)];
        }
        red[threadIdx.x]       = t0;
        red[256 + threadIdx.x] = t1;
        __syncthreads();
        for (int off = 128; off > 0; off >>= 1) {
            if (threadIdx.x < off) {
                red[threadIdx.x]       += red[threadIdx.x + off];
                red[256 + threadIdx.x] += red[256 + threadIdx.x + off];
            }
            __syncthreads();
        }
        if (threadIdx.x == 0) {
            double* pv = part + (((size_t)s * B_ + b) * 2) * MPAD;
            pv[2048]        = red[0];
            pv[MPAD + 2048] = red[256];
        }
    }
}

// ===========================================================================
// Kernel 3: FMM_QB blocks per batch.  Stage conv[b] = sum_s part[s][b] into
// LDS (redundant across the batch's blocks, but concurrent across 64 CUs),
// then fmm gather: 1 point/thread, 69 taps from LDS.
// ===========================================================================
__global__ __launch_bounds__(256)
void reduce_fmm(const float* __restrict__ x, const double* __restrict__ part,
                float* __restrict__ out) {
    __shared__ double convs[2 * M_];    // 32.8 KB
    const int b   = blockIdx.x >> 2;    // / FMM_QB
    const int qb  = blockIdx.x & (FMM_QB - 1);
    const int tid = threadIdx.x;
    const size_t sstride = (size_t)B_ * 2 * MPAD;
    for (int ch = 0; ch < 2; ++ch) {
        const size_t off0 = ((size_t)b * 2 + ch) * MPAD;
        for (int m = tid; m < M_; m += 256) {
            double acc = 0.0;
            #pragma unroll
            for (int k = 0; k < CV_SPLIT; ++k)
                acc += part[(size_t)k * sstride + off0 + m];
            convs[ch * M_ + m] = acc;
        }
    }
    __syncthreads();
    const double du      = TWO_PI_ / (double)M_;
    const double inv4tau = 1.0 / (4.0 * TAU_);
    const int p  = (b << 10) + (qb << 8) + tid;     // global point id
    const double xv = (double)x[p];
    const double u  = xv * (TWO_PI_ / 10.0);
    int mc = (int)(xv * ((double)M_ / 10.0) + 0.5);
    int lo = mc - 34; if (lo < 0) lo = 0;
    int hi = mc + 34; if (hi > M_ - 1) hi = M_ - 1;
    double av0 = 0.0, av1 = 0.0;
    for (int m = lo; m <= hi; ++m) {
        double d = u - du * (double)m;
        double g = (double)__expf(-(float)(d * d * inv4tau));
        av0 += g * convs[m];
        av1 += g * convs[M_ + m];
    }
    out[p * 2 + 0] = (float)(av0 / (double)M_);
    out[p * 2 + 1] = (float)(av1 / (double)M_);
}

// ---------------------------------------------------------------------------
extern "C" void kernel_launch(void* const* d_in, const int* in_sizes, int n_in,
                              void* d_out, int out_size, void* d_ws, size_t ws_size,
                              hipStream_t stream) {
    (void)in_sizes; (void)n_in; (void)out_size; (void)ws_size;
    const float* x  = (const float*)d_in[0];
    const float* s0 = (const float*)d_in[1];
    const float* a0 = (const float*)d_in[2];
    const float* s1 = (const float*)d_in[3];
    const float* a1 = (const float*)d_in[4];
    float* out = (float*)d_out;

    // Workspace (f64): [gsum_part GS_CH*B*M | hhalf 2*1025 | part]
    // No zeroing needed: every element is plain-stored by its owning block.
    double* gsum_part = (double*)d_ws;                     // 262272
    double* hhalf     = gsum_part + GS_CH * B_ * M_;       // 2050
    double* part      = hhalf + 2 * 1025;                  // 16*16*2*2052 (~8.4 MB)

    hipLaunchKernelGGL(spread_h3, dim3(GS_CH * B_ + HT_BLKS), dim3(256), 0, stream,
                       x, s0, a0, s1, a1, gsum_part, hhalf);
    hipLaunchKernelGGL(conv_kernel, dim3(2, CV_SPLIT, B_), dim3(256), 0, stream,
                       gsum_part, hhalf, part);
    hipLaunchKernelGGL(reduce_fmm, dim3(B_ * FMM_QB), dim3(256), 0, stream,
                       x, part, out);
}

// Round 4
// 89.058 us; speedup vs baseline: 1.3151x; 1.0981x over previous
//
#include <hip/hip_runtime.h>
#include <math.h>

#define M_   2049
#define B_   16
#define N_   1024
#define TAU_ 2.821e-5
#define PI_  3.14159265358979323846
#define TWO_PI_ 6.283185307179586476925286766559

#define CV_SPLIT 16     // mp-split for conv
#define MPAD     2052   // padded m-stride for conv partials (multiple of 4)

#define GS_CH    8      // scatter chunks per batch (128 blocks total)
#define HT_BLKS  65     // h d-tiles of 16 (65*16 = 1040 >= 1025)
#define FMM_LPP  16     // lanes per point in fmm_kernel

// LDS swizzle for the conv h-window: pad 1 double per 4 so the FIR
// lane-stride-4 read (word stride 8 -> 16-way conflict raw) becomes word
// stride 10 -> 4-way aliasing (~free). [R7: conflicts 6.4M->76K]
#define SW(i) ((i) + ((i) >> 2))

// ===========================================================================
// Kernel 1:
//  blocks [0,128): scatter chunk ch of batch b -> gsum_part[ch][b][:] (plain
//                  store; 128 pts/block, 2 lanes/pt, 34 taps -> proven scale).
//  blocks [128,193): h for a 16-wide d-tile, 16-way j-split in-block (64
//                  iters/thread), LDS reduce, plain store.  costab built via
//                  angle-addition (97 sincos, not 2049 cos).  No atomics.
// ===========================================================================
__global__ __launch_bounds__(256)
void spread_h4(const float* __restrict__ x,
               const float* __restrict__ s0, const float* __restrict__ a0,
               const float* __restrict__ s1, const float* __restrict__ a1,
               double* __restrict__ gsum_part, double* __restrict__ hhalf) {
    __shared__ double smem[4803];
    const int bx  = blockIdx.x;
    const int tid = threadIdx.x;

    if (bx < GS_CH * B_) {
        // ---- scatter partial: block owns gsum_part[ch][b][:] ----
        const int b  = bx >> 3;
        const int ch = bx & (GS_CH - 1);
        for (int i = tid; i < M_; i += 256) smem[i] = 0.0;
        __syncthreads();
        const int pl  = tid >> 1;          // local point 0..127
        const int sub = tid & 1;           // half-window 0/1
        const double du      = TWO_PI_ / (double)M_;
        const double inv4tau = 1.0 / (4.0 * TAU_);
        const double xv = (double)x[(b << 10) + (ch << 7) + pl];
        const double u  = xv * (TWO_PI_ / 10.0);
        const int mc = (int)(xv * ((double)M_ / 10.0) + 0.5);   // == u/du
        const int start = mc - 33 + sub * 34;                   // mc-33..mc+34
        for (int i = 0; i < 34; ++i) {
            int m = start + i;
            if (m >= 0 && m < M_) {
                double d = u - du * (double)m;
                double t = d * d * inv4tau;
                if (t < 88.0) atomicAdd(&smem[m], (double)__expf(-(float)t));
            }
        }
        __syncthreads();
        double* gp = gsum_part + ((size_t)ch * B_ + b) * M_;
        for (int i = tid; i < M_; i += 256) gp[i] = smem[i];
    } else {
        // ---- h tile: hhalf[d] = j0 + sum_j cf(j) cos(2pi j d / M) ----
        const int dtile = bx - GS_CH * B_;
        double* costab = smem;            // [0, 2049)
        double* cf0    = smem + 2049;     // [2049, 3073)
        double* cf1    = smem + 3073;     // [3073, 4097)
        double* red    = smem + 4097;     // [4097, 4609)
        double* cc     = smem + 4609;     // coarse cos [33]
        double* cs     = smem + 4642;     // coarse sin [33]
        double* fc     = smem + 4675;     // fine cos [64]
        double* fs     = smem + 4739;     // fine sin [64]
        const double th = TWO_PI_ / (double)M_;
        // 97 sincos instead of 2049 cos: costab[q*64+r] = cos(qP)cos(r t)-sin(qP)sin(r t)
        if (tid < 33) {
            double a = th * 64.0 * (double)tid;
            cc[tid] = cos(a);
            cs[tid] = sin(a);
        } else if (tid >= 64 && tid < 128) {
            double a = th * (double)(tid - 64);
            fc[tid - 64] = cos(a);
            fs[tid - 64] = sin(a);
        }
        const double sA = 5.0 * (double)s0[0], sB = 5.0 * (double)s1[0];
        const double amp0 = (double)a0[0],     amp1 = (double)a1[0];
        for (int jj = tid; jj < 1024; jj += 256) {
            double j  = (double)(jj + 1);
            double k2 = j * j;
            double dec2 = (PI_ / TAU_) * exp(2.0 * TAU_ * k2);   // deconv^2
            double base = 2.0 * (10.0 / TWO_PI_) * dec2 / (double)M_;
            cf0[jj] = base * (-amp0 * 4.0 * PI_ / (k2 + sA * sA));
            double den = k2 + sB * sB;
            cf1[jj] = base * (amp1 * 4.0 * PI_ / (den * den));
        }
        __syncthreads();
        for (int i = tid; i < M_; i += 256) {
            int q = i >> 6, r = i & 63;
            costab[i] = cc[q] * fc[r] - cs[q] * fs[r];
        }
        __syncthreads();
        const int dl = tid & 15;          // lane within d-tile
        const int jq = tid >> 4;          // j-sixteenth 0..15
        const int d  = (dtile << 4) + dl;
        double acc0 = 0.0, acc1 = 0.0;
        if (d <= 1024) {
            const int jlo = (jq << 6) + 1;
            int r = (int)(((long long)jlo * (long long)d) % M_);
            #pragma unroll 4
            for (int jj = 0; jj < 64; ++jj) {
                double cv_ = costab[r];
                acc0 += cf0[(jq << 6) + jj] * cv_;
                acc1 += cf1[(jq << 6) + jj] * cv_;
                r += d; if (r >= M_) r -= M_;
            }
        }
        red[tid]       = acc0;
        red[256 + tid] = acc1;
        __syncthreads();
        if (tid < 16) {
            const int dd = (dtile << 4) + tid;
            if (dd <= 1024) {
                const double w0base = (10.0 / TWO_PI_) * (PI_ / TAU_) / (double)M_;
                double h0 = w0base * (-amp0 * 4.0 * PI_ / (sA * sA));
                double h1 = w0base * (amp1 * 4.0 * PI_ / ((sB * sB) * (sB * sB)));
                #pragma unroll
                for (int q = 0; q < 16; ++q) {
                    h0 += red[(q << 4) + tid];
                    h1 += red[256 + (q << 4) + tid];
                }
                hhalf[dd]        = h0;
                hhalf[1025 + dd] = h1;
            }
        }
    }
}

// ===========================================================================
// Kernel 2: part[s][b][c][m] = sum over mp-chunk s of gsum[b][mp]*h_c[(m-mp)%M]
// FIR with swizzled LDS window; gsum chunk staged in LDS (summing the 8
// scatter partials); register-role-rotated 4-tap unroll (zero movs/tap).
// ===========================================================================
__global__ void conv_kernel(const double* __restrict__ gsum_part,
                            const double* __restrict__ hhalf,
                            double* __restrict__ part) {
    __shared__ double w0s[1456];        // SW(1153) max
    __shared__ double w1s[1456];
    __shared__ double red[512];
    __shared__ double gls[132];
    const int mt = blockIdx.x;          // 0 or 1
    const int s  = blockIdx.y;          // mp-chunk
    const int b  = blockIdx.z;
    const int m0  = mt * 1024;
    const int p0  = (s * M_) / CV_SPLIT;
    const int p1  = ((s + 1) * M_) / CV_SPLIT;
    const int len = p1 - p0;            // 128 or 129
    const int wcount = 1024 + len;
    int base = m0 - (p0 + len - 1);
    while (base < 0) base += M_;
    for (int i = threadIdx.x; i < wcount; i += 256) {
        int idx = base + i;
        while (idx >= M_) idx -= M_;
        int dd = (idx > 1024) ? (M_ - idx) : idx;   // h even: h[d]=hhalf[min(d,M-d)]
        w0s[SW(i)] = hhalf[dd];
        w1s[SW(i)] = hhalf[1025 + dd];
    }
    for (int i = threadIdx.x; i < len; i += 256) {
        double acc = 0.0;
        #pragma unroll
        for (int ch = 0; ch < GS_CH; ++ch)
            acc += gsum_part[((size_t)ch * B_ + b) * M_ + p0 + i];
        gls[i] = acc;
    }
    __syncthreads();

    const int q = 4 * threadIdx.x + len - 1;
    double A0 = w0s[SW(q)], A1 = w0s[SW(q+1)], A2 = w0s[SW(q+2)], A3 = w0s[SW(q+3)];
    double C0 = w1s[SW(q)], C1 = w1s[SW(q+1)], C2 = w1s[SW(q+2)], C3 = w1s[SW(q+3)];
    double a00=0.0,a01=0.0,a02=0.0,a03=0.0, a10=0.0,a11=0.0,a12=0.0,a13=0.0;
    int j = q, tt = 0;
    // Rotation: tap t, role r uses W(q - t + r); after 4 taps roles realign.
    for (; tt + 4 <= len; tt += 4) {
        double g;
        g = gls[tt];
        a00 += g*A0; a01 += g*A1; a02 += g*A2; a03 += g*A3;
        a10 += g*C0; a11 += g*C1; a12 += g*C2; a13 += g*C3;
        A3 = w0s[SW(j-1)]; C3 = w1s[SW(j-1)];
        g = gls[tt+1];
        a00 += g*A3; a01 += g*A0; a02 += g*A1; a03 += g*A2;
        a10 += g*C3; a11 += g*C0; a12 += g*C1; a13 += g*C2;
        A2 = w0s[SW(j-2)]; C2 = w1s[SW(j-2)];
        g = gls[tt+2];
        a00 += g*A2; a01 += g*A3; a02 += g*A0; a03 += g*A1;
        a10 += g*C2; a11 += g*C3; a12 += g*C0; a13 += g*C1;
        A1 = w0s[SW(j-3)]; C1 = w1s[SW(j-3)];
        g = gls[tt+3];
        a00 += g*A1; a01 += g*A2; a02 += g*A3; a03 += g*A0;
        a10 += g*C1; a11 += g*C2; a12 += g*C3; a13 += g*C0;
        A0 = w0s[SW(j-4)]; C0 = w1s[SW(j-4)];
        j -= 4;
    }
    for (; tt < len; ++tt) {            // tail: at most 1 (len = 128/129)
        double g = gls[tt];
        a00 += g*A0; a01 += g*A1; a02 += g*A2; a03 += g*A3;
        a10 += g*C0; a11 += g*C1; a12 += g*C2; a13 += g*C3;
    }
    {
        double* pv = part + (((size_t)s * B_ + b) * 2) * MPAD + m0 + 4 * threadIdx.x;
        pv[0]        = a00; pv[1]        = a01; pv[2]        = a02; pv[3]        = a03;
        pv[MPAD + 0] = a10; pv[MPAD + 1] = a11; pv[MPAD + 2] = a12; pv[MPAD + 3] = a13;
    }
    // m = 2048 side-reduction — mt==1 blocks only (mt uniform per block)
    if (mt == 1) {
        double t0 = 0.0, t1 = 0.0;
        if (threadIdx.x < len) {
            double g = gls[threadIdx.x];
            int qq = 1023 + len - threadIdx.x;
            t0 = g * w0s[SW(qq)];
            t1 = g * w1s[SW(qq)];
        }
        red[threadIdx.x]       = t0;
        red[256 + threadIdx.x] = t1;
        __syncthreads();
        for (int off = 128; off > 0; off >>= 1) {
            if (threadIdx.x < off) {
                red[threadIdx.x]       += red[threadIdx.x + off];
                red[256 + threadIdx.x] += red[256 + threadIdx.x + off];
            }
            __syncthreads();
        }
        if (threadIdx.x == 0) {
            double* pv = part + (((size_t)s * B_ + b) * 2) * MPAD;
            pv[2048]        = red[0];
            pv[MPAD + 2048] = red[256];
        }
    }
}

// ===========================================================================
// Kernel 3: conv[b][c][m] = sum_s part[s][b][c][m] — 16 independent coalesced
// loads per thread, plain stores.  257 blocks: massively parallel.
// ===========================================================================
__global__ void reduce_kernel(const double* __restrict__ part, double* __restrict__ conv) {
    const int idx = blockIdx.x * 256 + threadIdx.x;
    if (idx >= B_ * 2 * M_) return;
    const int b  = idx / (2 * M_);
    const int rm = idx - b * 2 * M_;       // c*M_ + m
    const int c  = rm / M_;
    const int m  = rm - c * M_;
    const size_t off = ((size_t)b * 2 + c) * MPAD + m;
    const size_t sstride = (size_t)B_ * 2 * MPAD;
    double acc = 0.0;
    #pragma unroll
    for (int k = 0; k < CV_SPLIT; ++k)
        acc += part[(size_t)k * sstride + off];
    conv[idx] = acc;
}

// ===========================================================================
// Kernel 4: fmm[b][n][c] = (1/M) sum_m g[b,n,m] * conv[b][c][m]
// 16 lanes per point (1024 blocks); conv is L2-resident; shfl-xor reduce.
// ===========================================================================
__global__ void fmm_kernel(const float* __restrict__ x, const double* __restrict__ conv,
                           float* __restrict__ out) {
    const int gid = blockIdx.x * 256 + threadIdx.x;
    const int pt  = gid / FMM_LPP;     // point id = b*N + n
    const int sub = gid % FMM_LPP;
    const int b   = pt >> 10;          // / N_
    const double du      = TWO_PI_ / (double)M_;
    const double inv4tau = 1.0 / (4.0 * TAU_);
    const double xv = (double)x[pt];
    const double u  = xv * (TWO_PI_ / 10.0);
    int mc = (int)(xv * ((double)M_ / 10.0) + 0.5);   // == u/du, div-free
    int lo = mc - 34; if (lo < 0) lo = 0;
    int hi = mc + 34; if (hi > M_ - 1) hi = M_ - 1;
    const double* c0 = conv + (size_t)(b * 2) * M_;
    const double* c1 = c0 + M_;
    double a0 = 0.0, a1 = 0.0;
    for (int m = lo + sub; m <= hi; m += FMM_LPP) {
        double d = u - du * (double)m;
        double g = (double)__expf(-(float)(d * d * inv4tau));
        a0 += g * c0[m];
        a1 += g * c1[m];
    }
    a0 += __shfl_xor(a0, 1); a1 += __shfl_xor(a1, 1);
    a0 += __shfl_xor(a0, 2); a1 += __shfl_xor(a1, 2);
    a0 += __shfl_xor(a0, 4); a1 += __shfl_xor(a1, 4);
    a0 += __shfl_xor(a0, 8); a1 += __shfl_xor(a1, 8);
    if (sub == 0) {
        out[pt * 2 + 0] = (float)(a0 / (double)M_);
        out[pt * 2 + 1] = (float)(a1 / (double)M_);
    }
}

// ---------------------------------------------------------------------------
extern "C" void kernel_launch(void* const* d_in, const int* in_sizes, int n_in,
                              void* d_out, int out_size, void* d_ws, size_t ws_size,
                              hipStream_t stream) {
    (void)in_sizes; (void)n_in; (void)out_size; (void)ws_size;
    const float* x  = (const float*)d_in[0];
    const float* s0 = (const float*)d_in[1];
    const float* a0 = (const float*)d_in[2];
    const float* s1 = (const float*)d_in[3];
    const float* a1 = (const float*)d_in[4];
    float* out = (float*)d_out;

    // Workspace (f64): [gsum_part GS_CH*B*M | hhalf 2*1025 | conv B*2*M | part]
    // No zeroing needed: every element is plain-stored by its owning block.
    double* gsum_part = (double*)d_ws;                     // 262272
    double* hhalf     = gsum_part + GS_CH * B_ * M_;       // 2050
    double* conv      = hhalf + 2 * 1025;                  // 65568
    double* part      = conv + B_ * 2 * M_;                // 16*16*2*2052 (~8.4 MB)

    hipLaunchKernelGGL(spread_h4, dim3(GS_CH * B_ + HT_BLKS), dim3(256), 0, stream,
                       x, s0, a0, s1, a1, gsum_part, hhalf);
    hipLaunchKernelGGL(conv_kernel, dim3(2, CV_SPLIT, B_), dim3(256), 0, stream,
                       gsum_part, hhalf, part);
    hipLaunchKernelGGL(reduce_kernel, dim3((B_ * 2 * M_ + 255) / 256), dim3(256), 0, stream,
                       part, conv);
    hipLaunchKernelGGL(fmm_kernel, dim3(B_ * N_ * FMM_LPP / 256), dim3(256), 0, stream,
                       x, conv, out);
}